// Round 3
// baseline (226.664 us; speedup 1.0000x reference)
//
#include <hip/hip_runtime.h>
#include <hip/hip_bf16.h>
#include <cstdint>
#include <cstddef>

// Problem constants (L=256, C=20, LC=5120, BATCH=1024)
#define LCN 5120
#define BN  1024
#define CN  20
#define NT  32    // K-steps per 1024-wide chunk (BK=32)

typedef __attribute__((ext_vector_type(4))) float  floatx4;
typedef __attribute__((ext_vector_type(8))) short  shortx8;
typedef __attribute__((ext_vector_type(4))) unsigned short ushortx4;
typedef __attribute__((ext_vector_type(8))) unsigned short ushortx8;

static __device__ __forceinline__ unsigned short f2bf(float f) {
    __hip_bfloat16 h = __float2bfloat16(f);
    return *reinterpret_cast<unsigned short*>(&h);
}

static __device__ __forceinline__ void gload_lds16(const void* g, void* l) {
    __builtin_amdgcn_global_load_lds(
        (const __attribute__((address_space(1))) void*)g,
        (__attribute__((address_space(3))) void*)l,
        16, 0, 0);
}

// ---------------------------------------------------------------------------
// Pass 1: x-only prep. out[b] = theta_0 + dot(theta_lc, x[b]); Xb = bf16(x).
// (The theta convert/mask is fused into k_quad — no Tb intermediate.)
// ---------------------------------------------------------------------------
__global__ __launch_bounds__(256) void k_prep(
    const float* __restrict__ x,     // [1024,5120]
    const float* __restrict__ th0,   // [1]
    const float* __restrict__ thlc,  // [5120]
    unsigned short* __restrict__ Xg, // [1024,5120] bf16 x
    float*          __restrict__ out)
{
    const int tid = threadIdx.x;
    const int b = blockIdx.x;
    const floatx4* xr = reinterpret_cast<const floatx4*>(x + (size_t)b * LCN);
    const floatx4* tr = reinterpret_cast<const floatx4*>(thlc);
    ushortx4* xw = reinterpret_cast<ushortx4*>(Xg + (size_t)b * LCN);
    float s = 0.0f;
    for (int k = tid; k < LCN / 4; k += 256) {
        const floatx4 a = xr[k], t2 = tr[k];
        s += a[0] * t2[0] + a[1] * t2[1] + a[2] * t2[2] + a[3] * t2[3];
        ushortx4 o;
#pragma unroll
        for (int e = 0; e < 4; ++e) o[e] = f2bf(a[e]);
        xw[k] = o;
    }
#pragma unroll
    for (int off = 32; off > 0; off >>= 1) s += __shfl_down(s, off, 64);
    __shared__ float ws4[4];
    if ((tid & 63) == 0) ws4[tid >> 6] = s;
    __syncthreads();
    if (tid == 0) out[b] = th0[0] + ws4[0] + ws4[1] + ws4[2] + ws4[3];
}

// ---------------------------------------------------------------------------
// Pass 2: fused masked-GEMM + dot-reduce reading theta FP32 DIRECTLY.
//   quad[b] = sum_i x[b,i] * ( sum_j Theta[i,j] * (j >= jmin_i) * x[b,j] )
// 256x256 tile, BK=32, 8 waves (2M x 4N), K-chunks of 1024, 60 suffix chunks
// x 4 m-tiles = 240 blocks; m-siblings of a chunk share an XCD (bid%8 RR) so
// theta fp32 is HBM-fetched once and L2-served to the other three.
// B path (reg-staged, T14): plain fp32 loads -> mask+cvt in VALU ->
//   swizzled ds_write_b128. Two register sets, issued 3 steps ahead.
// A path: gload_lds from Xb with inverse-swizzled source segs (as before).
// Counted vmcnt (never 0 mid-loop): B-wait vmcnt(6), A-wait vmcnt(10).
// LDS SEGMENT SWIZZLE (0-conflict): seg g of row r at slot (g+(r>>1))&3;
// readers use seg (kq+(row>>1))&3.
// ---------------------------------------------------------------------------
__global__ __launch_bounds__(512, 2) void k_quad(
    const unsigned short* __restrict__ Xg,   // [1024][5120] bf16
    const float*          __restrict__ th,   // [5120][5120] fp32 theta_lclc
    float*                __restrict__ out)  // [1024]
{
    const int bid  = blockIdx.x;
    const int xcd  = bid & 7;
    const int slot = bid >> 3;
    const int m    = slot & 3;    // M tile (256 rows of batch)
    const int cl   = slot >> 2;   // chunk-local index on this XCD
    int qc = cl * 8 + xcd;        // chunk ordinal 0..59
    if (qc >= 60) return;

    // chunk ordinal -> (n-tile, k-chunk) over 1024-wide suffix chunks
    int n = 0, cs = 0;
    for (int t = 0; t < 20; ++t) {
        const int lmin = (256 * t) / CN;
        const int c0   = (CN * (lmin + 1)) / 1024;
        const int cnt  = 5 - c0;
        if (qc < cnt) { n = t; cs = c0 + qc; break; }
        qc -= cnt;
    }
    const int b0 = m * 256;
    const int n0 = n * 256;
    const int k0 = cs * 1024;

    __shared__ unsigned short As[2 * 256 * 32];   // dbuf A
    __shared__ unsigned short Bs[2 * 256 * 32];   // dbuf B
    __shared__ float partial[256];

    const int tid  = threadIdx.x;
    const int lane = tid & 63;
    const int w    = tid >> 6;        // wave 0..7
    const int wm   = w & 1;           // M half (128 rows)
    const int wn   = w >> 1;          // N quarter (64 cols)
    const int lrow = lane & 15;
    const int kq   = lane >> 4;       // 0..3

    if (tid < 256) partial[tid] = 0.0f;

    // ---- B staging constants (fixed per thread across all K-steps) ----
    const int br   = tid >> 1;                 // B row 0..255
    const int bp   = tid & 1;                  // which 16-elem half of the row
    const int bi   = n0 + br;
    const int jmin = (bi / CN) * CN + CN;      // mask: keep iff j >= jmin
    const float* bsrc = th + (size_t)bi * LCN;
    const int slot0 = ((2 * bp)     + (br >> 1)) & 3;
    const int slot1 = ((2 * bp + 1) + (br >> 1)) & 3;
    const int wadr0 = br * 32 + slot0 * 8;     // ushort units
    const int wadr1 = br * 32 + slot1 * 8;

    floatx4 acc[8][4];
#pragma unroll
    for (int mt = 0; mt < 8; ++mt)
#pragma unroll
        for (int nt = 0; nt < 4; ++nt) acc[mt][nt] = (floatx4)0.0f;

    int aoff[8], boff[4];
#pragma unroll
    for (int mt = 0; mt < 8; ++mt) {
        const int row = wm * 128 + mt * 16 + lrow;
        aoff[mt] = row * 32 + (((kq + (row >> 1)) & 3) << 3);
    }
#pragma unroll
    for (int nt = 0; nt < 4; ++nt) {
        const int row = wn * 64 + nt * 16 + lrow;
        boff[nt] = row * 32 + (((kq + (row >> 1)) & 3) << 3);
    }

    floatx4 S0a, S0b, S0c, S0d, S1a, S1b, S1c, S1d;

#define ISSUE_B(S, kc) do {                                                   \
    const float* p_ = bsrc + (kc) + bp * 16;                                  \
    S##a = *reinterpret_cast<const floatx4*>(p_);                             \
    S##b = *reinterpret_cast<const floatx4*>(p_ + 4);                         \
    S##c = *reinterpret_cast<const floatx4*>(p_ + 8);                         \
    S##d = *reinterpret_cast<const floatx4*>(p_ + 12);                        \
} while (0)

#define WRITEB(S, PARW, kcw) do {                                             \
    const int j0_ = (kcw) + bp * 16;                                          \
    ushortx8 o0_, o1_;                                                        \
    _Pragma("unroll")                                                         \
    for (int e = 0; e < 4; ++e) {                                             \
        o0_[e]     = (j0_ + e      >= jmin) ? f2bf(S##a[e]) : (unsigned short)0; \
        o0_[4 + e] = (j0_ + 4 + e  >= jmin) ? f2bf(S##b[e]) : (unsigned short)0; \
        o1_[e]     = (j0_ + 8 + e  >= jmin) ? f2bf(S##c[e]) : (unsigned short)0; \
        o1_[4 + e] = (j0_ + 12 + e >= jmin) ? f2bf(S##d[e]) : (unsigned short)0; \
    }                                                                         \
    *reinterpret_cast<ushortx8*>(&Bs[(PARW) * 8192 + wadr0]) = o0_;           \
    *reinterpret_cast<ushortx8*>(&Bs[(PARW) * 8192 + wadr1]) = o1_;           \
} while (0)

#define ISSUE_A(PARA, kc) do {                                                \
    _Pragma("unroll")                                                         \
    for (int t_ = 0; t_ < 2; ++t_) {                                          \
        const int s_   = t_ * 512 + tid;                                      \
        const int row_ = s_ >> 2;                                             \
        const int g_   = ((s_ & 3) - (row_ >> 1)) & 3;                        \
        char* la_ = (char*)As + (PARA) * 16384 + (size_t)(t_ * 512 + w * 64) * 16; \
        gload_lds16(Xg + (size_t)(b0 + row_) * LCN + (kc) + g_ * 8, la_);     \
    }                                                                         \
} while (0)

    // ---- prologue: establish invariant for kk=0 ----
    ISSUE_B(S1, k0);                 // B step0 (temp in S1)
    ISSUE_A(0, k0);                  // A step0 -> buf0
    asm volatile("s_waitcnt vmcnt(2)" ::: "memory");   // B0 regs landed
    WRITEB(S1, 0, k0);               // B0 -> Bbuf0
    ISSUE_B(S0, k0 + 32);            // B step1 (consumed at kk=0)
    ISSUE_A(1, k0 + 32);             // A step1 -> buf1
    ISSUE_B(S1, k0 + 64);            // B step2 (consumed at kk=1)
    asm volatile("s_waitcnt vmcnt(10)" ::: "memory");  // A0 in LDS
    asm volatile("s_waitcnt lgkmcnt(0)" ::: "memory"); // B0 writes done
    __builtin_amdgcn_s_barrier();

    // ---- main loop; body parity static via step-2 unroll (rule #20) ----
#define BODY(kk, PAR, S) do {                                                 \
    shortx8 bfv[4], afv[8];                                                   \
    _Pragma("unroll")                                                         \
    for (int nt = 0; nt < 4; ++nt)                                            \
        bfv[nt] = *reinterpret_cast<const shortx8*>(&Bs[(PAR) * 8192 + boff[nt]]); \
    _Pragma("unroll")                                                         \
    for (int mt = 0; mt < 8; ++mt)                                            \
        afv[mt] = *reinterpret_cast<const shortx8*>(&As[(PAR) * 8192 + aoff[mt]]); \
    asm volatile("s_waitcnt lgkmcnt(0)" ::: "memory");  /* my frag reads done */ \
    __builtin_amdgcn_s_barrier();                       /* all waves done w/ cur */ \
    if ((kk) < NT - 2) { asm volatile("s_waitcnt vmcnt(6)" ::: "memory"); }   \
    else               { asm volatile("s_waitcnt vmcnt(2)" ::: "memory"); }   \
    if ((kk) + 1 < NT) WRITEB(S, (PAR) ^ 1, k0 + ((kk) + 1) * 32);            \
    if ((kk) + 2 < NT) ISSUE_A(PAR, k0 + ((kk) + 2) * 32);                    \
    if ((kk) + 3 < NT) ISSUE_B(S, k0 + ((kk) + 3) * 32);                      \
    _Pragma("unroll")                                                         \
    for (int mt = 0; mt < 8; ++mt)                                            \
        _Pragma("unroll")                                                     \
        for (int nt = 0; nt < 4; ++nt)                                        \
            acc[mt][nt] = __builtin_amdgcn_mfma_f32_16x16x32_bf16(afv[mt], bfv[nt], acc[mt][nt], 0, 0, 0); \
    if ((kk) < NT - 3)       { asm volatile("s_waitcnt vmcnt(10)" ::: "memory"); } \
    else if ((kk) == NT - 3) { asm volatile("s_waitcnt vmcnt(6)"  ::: "memory"); } \
    else                     { asm volatile("s_waitcnt vmcnt(0)"  ::: "memory"); } \
    asm volatile("s_waitcnt lgkmcnt(0)" ::: "memory");  /* my B writes done */ \
    __builtin_amdgcn_s_barrier();                       /* next buf ready */   \
} while (0)

    for (int kk = 0; kk < NT; kk += 2) {
        BODY(kk, 0, S0);
        BODY(kk + 1, 1, S1);
    }
#undef BODY
#undef ISSUE_A
#undef WRITEB
#undef ISSUE_B

    // Epilogue: C/D layout col = lane&15 (i), row = (lane>>4)*4 + reg (b)
#pragma unroll
    for (int mt = 0; mt < 8; ++mt) {
#pragma unroll
        for (int r = 0; r < 4; ++r) {
            const int b = b0 + wm * 128 + mt * 16 + kq * 4 + r;
            float s = 0.0f;
#pragma unroll
            for (int nt = 0; nt < 4; ++nt) {
                const int i = n0 + wn * 64 + nt * 16 + lrow;
                const __hip_bfloat16 hv = *reinterpret_cast<const __hip_bfloat16*>(&Xg[(size_t)b * LCN + i]);
                s += acc[mt][nt][r] * __bfloat162float(hv);
            }
            s += __shfl_xor(s, 1, 64);
            s += __shfl_xor(s, 2, 64);
            s += __shfl_xor(s, 4, 64);
            s += __shfl_xor(s, 8, 64);
            if (lrow == 0) atomicAdd(&partial[b - b0], s);
        }
    }
    __syncthreads();
    if (tid < 256) atomicAdd(&out[b0 + tid], partial[tid]);
}

// ---------------------------------------------------------------------------
extern "C" void kernel_launch(void* const* d_in, const int* in_sizes, int n_in,
                              void* d_out, int out_size, void* d_ws, size_t ws_size,
                              hipStream_t stream) {
    const float* x      = (const float*)d_in[0];  // [1024, 5120]
    const float* th0    = (const float*)d_in[1];  // [1]
    const float* thlc   = (const float*)d_in[2];  // [5120]
    const float* thlclc = (const float*)d_in[3];  // [5120, 5120]
    float* out = (float*)d_out;                   // [1024]

    // ws layout: Xb (bf16 1024x5120 = 10.5 MB) — no theta intermediate
    unsigned short* Xb = (unsigned short*)d_ws;

    k_prep<<<dim3(BN), 256, 0, stream>>>(x, th0, thlc, Xb, out);

    // 60 chunks x 4 m-tiles, padded to 8 chunk-slots per XCD: 8*8*4 = 256 blocks
    k_quad<<<dim3(256), 512, 0, stream>>>(Xb, thlclc, out);
}